// Round 5
// baseline (246.373 us; speedup 1.0000x reference)
//
#include <hip/hip_runtime.h>
#include <float.h>

#define TPB  512           // 8 waves/block × 4 blocks/CU = 32 waves/CU
#define KTOP 32
#define GCAP 512           // post-cmask bin capacity (E[187], 24 sigma)
#define LCAP 1024          // pre-cmask stash capacity (E[373], 34 sigma)
// Output buffer is f32; harness compares after bf16-casting both sides.
// Sentinel must bf16-round FINITE: 0xFF7F0000 -> bf16 0xFF7F (largest finite neg).
#define SENT_U32 0xFF7F0000u
#define VCLAMP 3.0e38f
// scores ~ N(0,1); P(s>=2.0)=2.28%. Segment ~16384 edges -> stash E=373
// (sigma 19); after cmask p=0.5 -> S E=187 (sigma 13.6). Fast path needs
// stash<=LCAP and KTOP<=S<=GCAP; any violation -> exact radix fallback.
#define STHRESH 2.0f

typedef float floatx4 __attribute__((ext_vector_type(4)));

__device__ __forceinline__ unsigned int f2u(float f){
  unsigned int u = __float_as_uint(f);
  return (u & 0x80000000u) ? ~u : (u | 0x80000000u);
}

// ---------------- fallback helpers (exact radix select) ----------------
__device__ int suffix_total(int* hist, int NB, int* gsum, int tid){
  int GS = NB >> 8;
  if (tid < 256){
    int p = 0, base = tid * GS;
    for (int j = 0; j < GS; ++j) p += hist[base + j];
    gsum[tid] = p;
  }
  __syncthreads();
  for (int d = 1; d < 256; d <<= 1){
    int v = 0;
    if (tid < 256) v = (tid + d < 256) ? gsum[tid + d] : 0;
    __syncthreads();
    if (tid < 256) gsum[tid] += v;
    __syncthreads();
  }
  return gsum[0];
}

__device__ int find_bin(int* hist, int NB, int* gsum, int R, int* s2, int tid,
                        int* above_out){
  int GS = NB >> 8;
  if (tid < 256){
    int St  = gsum[tid];
    int St1 = (tid < 255) ? gsum[tid + 1] : 0;
    if (R > St1 && R <= St) s2[0] = tid;   // unique writer (gsum non-increasing)
  }
  __syncthreads();
  if (tid == 0){
    int G = s2[0];
    int above = (G < 255) ? gsum[G + 1] : 0;
    int b = (G + 1) * GS - 1;
    for (; b > G * GS; --b){
      int h = hist[b];
      if (above + h >= R) break;
      above += h;
    }
    s2[0] = b; s2[1] = above;
  }
  __syncthreads();
  int bin = s2[0];
  *above_out = s2[1];
  __syncthreads();
  return bin;
}

__global__ void __launch_bounds__(TPB, 8)
fused_kernel(const float* __restrict__ logits,
             const float* __restrict__ scores,
             const float* __restrict__ stop_logits,
             const int* __restrict__ batch,
             const int* __restrict__ cmask,
             float* __restrict__ out, int E, int NG)
{
  __shared__ int hist[2048];        // fallback only
  __shared__ int gsum[256];
  __shared__ int s2[2];
  __shared__ int sbounds[2];
  __shared__ int srch[2];
  __shared__ unsigned int st_u[LCAP];   // pre-cmask stash (score>=THR)
  __shared__ int st_i[LCAP];
  __shared__ unsigned int bin_u[GCAP];  // post-cmask candidates
  __shared__ int bin_i[GCAP];
  __shared__ int ab_i[KTOP];
  __shared__ int vidx[KTOP];
  __shared__ float vlog[KTOP];
  __shared__ int scnt, cnt_bin, cnt_ab, vcnt;
  __shared__ float sh_logden;

  int tid = threadIdx.x;
  int g = blockIdx.x;

  // ---- segment bounds: cooperative 256-ary search (2 groups of 256) ----
  {
    int grp = tid >> 8 & 1;        // group 0: lower_bound(g); group 1: lower_bound(g+1)
    int lt  = tid & 255;
    int target = g + grp;
    int lo = 0, hi = E;            // invariant: batch[lo-1] < target <= batch[hi]
    for (int round = 0; round < 3; ++round){
      if (lt == 0) srch[grp] = 0;
      __syncthreads();
      int width = hi - lo;
      int pred = 0;
      if (width > 256){
        long long w = width;
        int q = lo + (int)((w * (long long)lt) >> 8);   // q_0 = lo, all q < hi
        pred = (batch[q] < target) ? 1 : 0;
      }
      unsigned long long bal = __ballot(pred);
      if ((tid & 63) == 0) atomicAdd(&srch[grp], __popcll(bal));
      __syncthreads();
      if (width > 256){
        long long w = width;
        int c = srch[grp];         // preds are a prefix (batch sorted)
        int nlo = (c > 0)   ? lo + (int)((w * (long long)(c - 1)) >> 8) + 1 : lo;
        int nhi = (c < 256) ? lo + (int)((w * (long long)c) >> 8)          : hi;
        lo = nlo; hi = nhi;
      }
      __syncthreads();
    }
    if (lt == 0) srch[grp] = 0;
    __syncthreads();
    int width = hi - lo;
    int pred = (lt < width) ? ((batch[lo + lt] < target) ? 1 : 0) : 0;
    unsigned long long bal = __ballot(pred);
    if ((tid & 63) == 0) atomicAdd(&srch[grp], __popcll(bal));
    __syncthreads();
    if (lt == 0) sbounds[grp] = lo + srch[grp];
  }
  if (tid == 0){ scnt = 0; cnt_bin = 0; cnt_ab = 0; vcnt = 0; }
  __syncthreads();
  int s = sbounds[0], e = sbounds[1];

  int s4 = (s + 3) & ~3; if (s4 > e) s4 = e;
  int e4 = e & ~3;       if (e4 < s4) e4 = s4;
  const float4* sc4 = (const float4*)scores;
  const float SENT = __uint_as_float(SENT_U32);
  floatx4 sv = { SENT, SENT, SENT, SENT };
  floatx4* out4 = (floatx4*)out;

  // ---- phase A: pure stream, bitmask-aggregated stash.
  // Per float4: pure-VALU 4-bit hit mask; ONE LDS atomic per lane only when
  // h!=0 (P=8.8%); <=4 predicated LDS writes. No per-element atomic chains
  // between the global loads -> loads stay pipelined at MLP=4.
  auto proc4 = [&](float4 a, int bidx){
    int h = (a.x >= STHRESH ? 1 : 0) | (a.y >= STHRESH ? 2 : 0)
          | (a.z >= STHRESH ? 4 : 0) | (a.w >= STHRESH ? 8 : 0);
    if (h){
      int sl = atomicAdd(&scnt, __popc(h));
      if (h & 1){ if (sl < LCAP){ st_u[sl] = f2u(a.x); st_i[sl] = bidx;     } sl++; }
      if (h & 2){ if (sl < LCAP){ st_u[sl] = f2u(a.y); st_i[sl] = bidx + 1; } sl++; }
      if (h & 4){ if (sl < LCAP){ st_u[sl] = f2u(a.z); st_i[sl] = bidx + 2; } sl++; }
      if (h & 8){ if (sl < LCAP){ st_u[sl] = f2u(a.w); st_i[sl] = bidx + 3; } }
    }
  };
  auto st1 = [&](float sc, int idx){     // scalar head/tail only
    if (sc >= STHRESH){
      int sl = atomicAdd(&scnt, 1);
      if (sl < LCAP){ st_u[sl] = f2u(sc); st_i[sl] = idx; }
    }
  };
  {
    int i = s + tid;  if (i < s4){ st1(scores[i], i); out[i] = SENT; }
    int j = e4 + tid; if (j < e) { st1(scores[j], j); out[j] = SENT; }
    int q  = (s4 >> 2) + tid;
    int qe = (e4 >> 2);
    // 4x-unrolled: 4 independent 16B loads in flight per thread
    for (; q + 3 * TPB < qe; q += 4 * TPB){
      float4 a0 = sc4[q];
      float4 a1 = sc4[q +     TPB];
      float4 a2 = sc4[q + 2 * TPB];
      float4 a3 = sc4[q + 3 * TPB];
      __builtin_nontemporal_store(sv, &out4[q]);
      __builtin_nontemporal_store(sv, &out4[q +     TPB]);
      __builtin_nontemporal_store(sv, &out4[q + 2 * TPB]);
      __builtin_nontemporal_store(sv, &out4[q + 3 * TPB]);
      proc4(a0, q << 2);
      proc4(a1, (q +     TPB) << 2);
      proc4(a2, (q + 2 * TPB) << 2);
      proc4(a3, (q + 3 * TPB) << 2);
    }
    for (; q < qe; q += TPB){
      float4 a = sc4[q];
      __builtin_nontemporal_store(sv, &out4[q]);
      proc4(a, q << 2);
    }
  }
  __syncthreads();

  // ---- phase B: batched cmask resolution (all scattered loads in parallel) ----
  int nst = scnt;
  bool ovf = (nst > LCAP);
  if (!ovf){
    for (int t = tid; t < nst; t += TPB){
      int idx = st_i[t];
      if (cmask[idx]){
        int sl = atomicAdd(&cnt_bin, 1);
        if (sl < GCAP){ bin_u[sl] = st_u[t]; bin_i[sl] = idx; }
      }
    }
  }
  __syncthreads();
  int S = cnt_bin;

  if (!ovf && S >= KTOP && S <= GCAP){
    // ---- FAST PATH (exact): every candidate outside bin has score < THR,
    // and bin holds >= KTOP candidates with score >= THR => top-32 subset of bin.
    // Rank by (u desc, idx asc) — matches reference stable argsort tie-break.
    for (int jj = tid; jj < S; jj += TPB){
      unsigned long long kj = ((unsigned long long)bin_u[jj] << 32)
                            | (unsigned long long)(unsigned)(~(unsigned)bin_i[jj]);
      int rank = 0;
      for (int k = 0; k < S; ++k){
        unsigned long long kk = ((unsigned long long)bin_u[k] << 32)
                              | (unsigned long long)(unsigned)(~(unsigned)bin_i[k]);
        rank += (kk > kj) ? 1 : 0;
      }
      if (rank < KTOP){
        int sl = atomicAdd(&vcnt, 1);
        if (sl < KTOP) vidx[sl] = bin_i[jj];   // exactly KTOP ranks < KTOP
      }
    }
  } else {
    // ---- FALLBACK (exact, rare): full radix top-k with dense cmask reads ----
    auto scan_sc = [&](auto&& fn){
      int i = s + tid;  if (i < s4) fn(scores[i], i);
      int j = e4 + tid; if (j < e)  fn(scores[j], j);
      for (int q = (s4 >> 2) + tid, qe = (e4 >> 2); q < qe; q += TPB){
        float4 sc = sc4[q];
        int base = q << 2;
        fn(sc.x, base);     fn(sc.y, base + 1);
        fn(sc.z, base + 2); fn(sc.w, base + 3);
      }
    };
    auto is_cand = [&](int idx) -> bool { return cmask[idx] != 0; };

    for (int b = tid; b < 2048; b += TPB) hist[b] = 0;
    if (tid == 0){ cnt_bin = 0; cnt_ab = 0; }
    __syncthreads();
    scan_sc([&](float sc, int idx){
      if (is_cand(idx)) atomicAdd(&hist[f2u(sc) >> 21], 1);
    });
    __syncthreads();
    int T = suffix_total(hist, 2048, gsum, tid);
    bool sel = (T > KTOP);
    unsigned int prefix = 0; int pshift = 32; int R = KTOP;
    if (sel){
      int above;
      int b1 = find_bin(hist, 2048, gsum, R, s2, tid, &above);
      R -= above; prefix = (unsigned)b1; pshift = 21;
      int hcnt = hist[b1];
      __syncthreads();
      if (hcnt > GCAP){                       // refine bits [20:10]
        for (int b = tid; b < 2048; b += TPB) hist[b] = 0;
        __syncthreads();
        scan_sc([&](float sc, int idx){
          unsigned u = f2u(sc);
          if ((u >> 21) == prefix && is_cand(idx))
            atomicAdd(&hist[(u >> 10) & 0x7FFu], 1);
        });
        __syncthreads();
        suffix_total(hist, 2048, gsum, tid);
        int b2 = find_bin(hist, 2048, gsum, R, s2, tid, &above);
        R -= above; prefix = (prefix << 11) | (unsigned)b2; pshift = 10;
        hcnt = hist[b2];
        __syncthreads();
        if (hcnt > GCAP){                     // final bits [9:0]
          for (int b = tid; b < 1024; b += TPB) hist[b] = 0;
          __syncthreads();
          scan_sc([&](float sc, int idx){
            unsigned u = f2u(sc);
            if ((u >> 10) == prefix && is_cand(idx))
              atomicAdd(&hist[u & 0x3FFu], 1);
          });
          __syncthreads();
          suffix_total(hist, 1024, gsum, tid);
          int b3 = find_bin(hist, 1024, gsum, R, s2, tid, &above);
          R -= above; prefix = (prefix << 10) | (unsigned)b3; pshift = 0;
          __syncthreads();
        }
      }
      scan_sc([&](float sc, int idx){
        unsigned u = f2u(sc);
        unsigned hp = (pshift < 32) ? (u >> pshift) : 0u;
        if (hp >= prefix){
          if (is_cand(idx)){
            if (hp == prefix){
              int sl = atomicAdd(&cnt_bin, 1);
              if (sl < GCAP){ bin_u[sl] = u; bin_i[sl] = idx; }
            } else {
              int sl = atomicAdd(&cnt_ab, 1);
              if (sl < KTOP) ab_i[sl] = idx;  // strictly-above count < R <= 32
            }
          }
        }
      });
      __syncthreads();
      int bn = min(cnt_bin, GCAP);
      for (int jj = tid; jj < bn; jj += TPB){
        unsigned long long kj = ((unsigned long long)bin_u[jj] << 32)
                              | (unsigned long long)(unsigned)(~(unsigned)bin_i[jj]);
        int rank = 0;
        for (int k = 0; k < bn; ++k){
          unsigned long long kk2 = ((unsigned long long)bin_u[k] << 32)
                                 | (unsigned long long)(unsigned)(~(unsigned)bin_i[k]);
          rank += (kk2 > kj) ? 1 : 0;
        }
        if (rank < R){
          int sl = atomicAdd(&vcnt, 1);
          if (sl < KTOP) vidx[sl] = bin_i[jj];
        }
      }
      int na = min(cnt_ab, KTOP);
      for (int jj = tid; jj < na; jj += TPB){
        int sl = atomicAdd(&vcnt, 1);
        if (sl < KTOP) vidx[sl] = ab_i[jj];
      }
    } else {
      // T <= 32: every candidate is valid
      scan_sc([&](float sc, int idx){
        (void)sc;
        if (is_cand(idx)){
          int sl = atomicAdd(&vcnt, 1);
          if (sl < KTOP) vidx[sl] = idx;
        }
      });
    }
  }
  __syncthreads();

  // ---- LSE over the <=32 valid logits (wave 0, shuffle-parallel) ----
  int c = min(vcnt, KTOP);
  if (tid < c) vlog[tid] = logits[vidx[tid]];
  __syncthreads();
  if (tid < 64){
    float v = (tid < c) ? vlog[tid] : -FLT_MAX;
    float m = v;
    #pragma unroll
    for (int d = 32; d; d >>= 1) m = fmaxf(m, __shfl_xor(m, d));
    float ex = (tid < c) ? expf(v - m) : 0.f;
    #pragma unroll
    for (int d = 32; d; d >>= 1) ex += __shfl_xor(ex, d);
    if (tid == 0){
      float stop = stop_logits[g];              // TEMP == 1.0
      float logden;
      if (c == 0){
        logden = stop;                          // logaddexp(~-inf, stop) = stop
      } else {
        float lse = logf(fmaxf(ex, FLT_EPSILON)) + m;   // eps clamp per reference
        float mx = fmaxf(lse, stop);
        float dd = fabsf(lse - stop);
        logden = mx + log1pf(expf(-dd));        // logaddexp(lse, stop)
      }
      sh_logden = logden;
    }
  }
  __syncthreads();

  // ---- scatter the <=32 valid log-probs over the sentinel fill ----
  if (tid < c){
    float val = vlog[tid] - sh_logden;
    if (!(val >= -VCLAMP)) val = -VCLAMP;       // flushes NaN too
    if (val > VCLAMP)      val =  VCLAMP;
    out[vidx[tid]] = val;
  }
}

extern "C" void kernel_launch(void* const* d_in, const int* in_sizes, int n_in,
                              void* d_out, int out_size, void* d_ws, size_t ws_size,
                              hipStream_t stream){
  const float* edge_logits = (const float*)d_in[0];
  const float* edge_scores = (const float*)d_in[1];
  const float* stop_logits = (const float*)d_in[2];
  const int*   edge_batch  = (const int*)d_in[3];
  const int*   cmask       = (const int*)d_in[4];
  int E  = in_sizes[0];
  int NG = in_sizes[2];
  float* out = (float*)d_out;
  (void)d_ws; (void)ws_size;

  hipLaunchKernelGGL(fused_kernel, dim3(NG), dim3(TPB), 0, stream,
                     edge_logits, edge_scores, stop_logits, edge_batch, cmask,
                     out, E, NG);
}

// Round 6
// 237.491 us; speedup vs baseline: 1.0374x; 1.0374x over previous
//
#include <hip/hip_runtime.h>
#include <float.h>

#define TPB  512           // 8 waves/block
#define KTOP 32
#define GCAP 512           // post-cmask bin capacity (E[187], 24 sigma)
#define LCAP 1024          // pre-cmask stash capacity (E[373], 34 sigma)
// Output buffer is f32; harness compares after bf16-casting both sides.
// Sentinel must bf16-round FINITE: 0xFF7F0000 -> bf16 0xFF7F (largest finite neg).
#define SENT_U32 0xFF7F0000u
#define VCLAMP 3.0e38f
// scores ~ N(0,1); P(s>=2.0)=2.28%. Segment ~16384 edges -> stash E=373
// (sigma 19); after cmask p=0.5 -> S E=187 (sigma 13.6). Fast path needs
// stash<=LCAP and KTOP<=S<=GCAP; any violation -> exact radix fallback.
#define STHRESH 2.0f

__device__ __forceinline__ unsigned int f2u(float f){
  unsigned int u = __float_as_uint(f);
  return (u & 0x80000000u) ? ~u : (u | 0x80000000u);
}

// ---------------- fallback helpers (exact radix select) ----------------
__device__ int suffix_total(int* hist, int NB, int* gsum, int tid){
  int GS = NB >> 8;
  if (tid < 256){
    int p = 0, base = tid * GS;
    for (int j = 0; j < GS; ++j) p += hist[base + j];
    gsum[tid] = p;
  }
  __syncthreads();
  for (int d = 1; d < 256; d <<= 1){
    int v = 0;
    if (tid < 256) v = (tid + d < 256) ? gsum[tid + d] : 0;
    __syncthreads();
    if (tid < 256) gsum[tid] += v;
    __syncthreads();
  }
  return gsum[0];
}

__device__ int find_bin(int* hist, int NB, int* gsum, int R, int* s2, int tid,
                        int* above_out){
  int GS = NB >> 8;
  if (tid < 256){
    int St  = gsum[tid];
    int St1 = (tid < 255) ? gsum[tid + 1] : 0;
    if (R > St1 && R <= St) s2[0] = tid;   // unique writer (gsum non-increasing)
  }
  __syncthreads();
  if (tid == 0){
    int G = s2[0];
    int above = (G < 255) ? gsum[G + 1] : 0;
    int b = (G + 1) * GS - 1;
    for (; b > G * GS; --b){
      int h = hist[b];
      if (above + h >= R) break;
      above += h;
    }
    s2[0] = b; s2[1] = above;
  }
  __syncthreads();
  int bin = s2[0];
  *above_out = s2[1];
  __syncthreads();
  return bin;
}

__global__ void __launch_bounds__(TPB, 4)   // VGPR cap 128: let the 4-deep load pipe live
fused_kernel(const float* __restrict__ logits,
             const float* __restrict__ scores,
             const float* __restrict__ stop_logits,
             const int* __restrict__ batch,
             const int* __restrict__ cmask,
             float* __restrict__ out, int E, int NG)
{
  __shared__ int hist[2048];        // fallback only
  __shared__ int gsum[256];
  __shared__ int s2[2];
  __shared__ int sbounds[2];
  __shared__ int srch[2];
  __shared__ unsigned int st_u[LCAP];   // pre-cmask stash (score>=THR)
  __shared__ int st_i[LCAP];
  __shared__ unsigned int bin_u[GCAP];  // post-cmask candidates
  __shared__ int bin_i[GCAP];
  __shared__ int ab_i[KTOP];
  __shared__ int vidx[KTOP];
  __shared__ float vlog[KTOP];
  __shared__ int scnt, cnt_bin, cnt_ab, vcnt;
  __shared__ float sh_logden;

  int tid = threadIdx.x;
  int g = blockIdx.x;

  // ---- segment bounds: cooperative 256-ary search (2 groups of 256) ----
  {
    int grp = tid >> 8 & 1;        // group 0: lower_bound(g); group 1: lower_bound(g+1)
    int lt  = tid & 255;
    int target = g + grp;
    int lo = 0, hi = E;            // invariant: batch[lo-1] < target <= batch[hi]
    for (int round = 0; round < 3; ++round){
      if (lt == 0) srch[grp] = 0;
      __syncthreads();
      int width = hi - lo;
      int pred = 0;
      if (width > 256){
        long long w = width;
        int q = lo + (int)((w * (long long)lt) >> 8);   // q_0 = lo, all q < hi
        pred = (batch[q] < target) ? 1 : 0;
      }
      unsigned long long bal = __ballot(pred);
      if ((tid & 63) == 0) atomicAdd(&srch[grp], __popcll(bal));
      __syncthreads();
      if (width > 256){
        long long w = width;
        int c = srch[grp];         // preds are a prefix (batch sorted)
        int nlo = (c > 0)   ? lo + (int)((w * (long long)(c - 1)) >> 8) + 1 : lo;
        int nhi = (c < 256) ? lo + (int)((w * (long long)c) >> 8)          : hi;
        lo = nlo; hi = nhi;
      }
      __syncthreads();
    }
    if (lt == 0) srch[grp] = 0;
    __syncthreads();
    int width = hi - lo;
    int pred = (lt < width) ? ((batch[lo + lt] < target) ? 1 : 0) : 0;
    unsigned long long bal = __ballot(pred);
    if ((tid & 63) == 0) atomicAdd(&srch[grp], __popcll(bal));
    __syncthreads();
    if (lt == 0) sbounds[grp] = lo + srch[grp];
  }
  if (tid == 0){ scnt = 0; cnt_bin = 0; cnt_ab = 0; vcnt = 0; }
  __syncthreads();
  int s = sbounds[0], e = sbounds[1];

  int s4 = (s + 3) & ~3; if (s4 > e) s4 = e;
  int e4 = e & ~3;       if (e4 < s4) e4 = s4;
  const float4* sc4 = (const float4*)scores;
  const float SENT = __uint_as_float(SENT_U32);
  const float4 sv = make_float4(SENT, SENT, SENT, SENT);
  float4* out4 = (float4*)out;

  // ---- phase A: pure stream, bitmask-aggregated stash.
  // Plain (L2-buffered) sentinel stores: stores ack in L2, so the in-order
  // vmcnt waits before consuming loads never chain to HBM write-drain.
  auto proc4 = [&](float4 a, int bidx){
    int h = (a.x >= STHRESH ? 1 : 0) | (a.y >= STHRESH ? 2 : 0)
          | (a.z >= STHRESH ? 4 : 0) | (a.w >= STHRESH ? 8 : 0);
    if (h){
      int sl = atomicAdd(&scnt, __popc(h));
      if (h & 1){ if (sl < LCAP){ st_u[sl] = f2u(a.x); st_i[sl] = bidx;     } sl++; }
      if (h & 2){ if (sl < LCAP){ st_u[sl] = f2u(a.y); st_i[sl] = bidx + 1; } sl++; }
      if (h & 4){ if (sl < LCAP){ st_u[sl] = f2u(a.z); st_i[sl] = bidx + 2; } sl++; }
      if (h & 8){ if (sl < LCAP){ st_u[sl] = f2u(a.w); st_i[sl] = bidx + 3; } }
    }
  };
  auto st1 = [&](float sc, int idx){     // scalar head/tail only
    if (sc >= STHRESH){
      int sl = atomicAdd(&scnt, 1);
      if (sl < LCAP){ st_u[sl] = f2u(sc); st_i[sl] = idx; }
    }
  };
  {
    int i = s + tid;  if (i < s4){ st1(scores[i], i); out[i] = SENT; }
    int j = e4 + tid; if (j < e) { st1(scores[j], j); out[j] = SENT; }
    int q  = (s4 >> 2) + tid;
    int qe = (e4 >> 2);
    // 4x-unrolled: 4 independent 16B loads in flight per thread
    for (; q + 3 * TPB < qe; q += 4 * TPB){
      float4 a0 = sc4[q];
      float4 a1 = sc4[q +     TPB];
      float4 a2 = sc4[q + 2 * TPB];
      float4 a3 = sc4[q + 3 * TPB];
      out4[q]           = sv;
      out4[q +     TPB] = sv;
      out4[q + 2 * TPB] = sv;
      out4[q + 3 * TPB] = sv;
      proc4(a0, q << 2);
      proc4(a1, (q +     TPB) << 2);
      proc4(a2, (q + 2 * TPB) << 2);
      proc4(a3, (q + 3 * TPB) << 2);
    }
    for (; q < qe; q += TPB){
      float4 a = sc4[q];
      out4[q] = sv;
      proc4(a, q << 2);
    }
  }
  __syncthreads();

  // ---- phase B: batched cmask resolution (all scattered loads in parallel) ----
  int nst = scnt;
  bool ovf = (nst > LCAP);
  if (!ovf){
    for (int t = tid; t < nst; t += TPB){
      int idx = st_i[t];
      if (cmask[idx]){
        int sl = atomicAdd(&cnt_bin, 1);
        if (sl < GCAP){ bin_u[sl] = st_u[t]; bin_i[sl] = idx; }
      }
    }
  }
  __syncthreads();
  int S = cnt_bin;

  if (!ovf && S >= KTOP && S <= GCAP){
    // ---- FAST PATH (exact): every candidate outside bin has score < THR,
    // and bin holds >= KTOP candidates with score >= THR => top-32 subset of bin.
    // Rank by (u desc, idx asc) — matches reference stable argsort tie-break.
    for (int jj = tid; jj < S; jj += TPB){
      unsigned long long kj = ((unsigned long long)bin_u[jj] << 32)
                            | (unsigned long long)(unsigned)(~(unsigned)bin_i[jj]);
      int rank = 0;
      for (int k = 0; k < S; ++k){
        unsigned long long kk = ((unsigned long long)bin_u[k] << 32)
                              | (unsigned long long)(unsigned)(~(unsigned)bin_i[k]);
        rank += (kk > kj) ? 1 : 0;
      }
      if (rank < KTOP){
        int sl = atomicAdd(&vcnt, 1);
        if (sl < KTOP) vidx[sl] = bin_i[jj];   // exactly KTOP ranks < KTOP
      }
    }
  } else {
    // ---- FALLBACK (exact, rare): full radix top-k with dense cmask reads ----
    auto scan_sc = [&](auto&& fn){
      int i = s + tid;  if (i < s4) fn(scores[i], i);
      int j = e4 + tid; if (j < e)  fn(scores[j], j);
      for (int q = (s4 >> 2) + tid, qe = (e4 >> 2); q < qe; q += TPB){
        float4 sc = sc4[q];
        int base = q << 2;
        fn(sc.x, base);     fn(sc.y, base + 1);
        fn(sc.z, base + 2); fn(sc.w, base + 3);
      }
    };
    auto is_cand = [&](int idx) -> bool { return cmask[idx] != 0; };

    for (int b = tid; b < 2048; b += TPB) hist[b] = 0;
    if (tid == 0){ cnt_bin = 0; cnt_ab = 0; }
    __syncthreads();
    scan_sc([&](float sc, int idx){
      if (is_cand(idx)) atomicAdd(&hist[f2u(sc) >> 21], 1);
    });
    __syncthreads();
    int T = suffix_total(hist, 2048, gsum, tid);
    bool sel = (T > KTOP);
    unsigned int prefix = 0; int pshift = 32; int R = KTOP;
    if (sel){
      int above;
      int b1 = find_bin(hist, 2048, gsum, R, s2, tid, &above);
      R -= above; prefix = (unsigned)b1; pshift = 21;
      int hcnt = hist[b1];
      __syncthreads();
      if (hcnt > GCAP){                       // refine bits [20:10]
        for (int b = tid; b < 2048; b += TPB) hist[b] = 0;
        __syncthreads();
        scan_sc([&](float sc, int idx){
          unsigned u = f2u(sc);
          if ((u >> 21) == prefix && is_cand(idx))
            atomicAdd(&hist[(u >> 10) & 0x7FFu], 1);
        });
        __syncthreads();
        suffix_total(hist, 2048, gsum, tid);
        int b2 = find_bin(hist, 2048, gsum, R, s2, tid, &above);
        R -= above; prefix = (prefix << 11) | (unsigned)b2; pshift = 10;
        hcnt = hist[b2];
        __syncthreads();
        if (hcnt > GCAP){                     // final bits [9:0]
          for (int b = tid; b < 1024; b += TPB) hist[b] = 0;
          __syncthreads();
          scan_sc([&](float sc, int idx){
            unsigned u = f2u(sc);
            if ((u >> 10) == prefix && is_cand(idx))
              atomicAdd(&hist[u & 0x3FFu], 1);
          });
          __syncthreads();
          suffix_total(hist, 1024, gsum, tid);
          int b3 = find_bin(hist, 1024, gsum, R, s2, tid, &above);
          R -= above; prefix = (prefix << 10) | (unsigned)b3; pshift = 0;
          __syncthreads();
        }
      }
      scan_sc([&](float sc, int idx){
        unsigned u = f2u(sc);
        unsigned hp = (pshift < 32) ? (u >> pshift) : 0u;
        if (hp >= prefix){
          if (is_cand(idx)){
            if (hp == prefix){
              int sl = atomicAdd(&cnt_bin, 1);
              if (sl < GCAP){ bin_u[sl] = u; bin_i[sl] = idx; }
            } else {
              int sl = atomicAdd(&cnt_ab, 1);
              if (sl < KTOP) ab_i[sl] = idx;  // strictly-above count < R <= 32
            }
          }
        }
      });
      __syncthreads();
      int bn = min(cnt_bin, GCAP);
      for (int jj = tid; jj < bn; jj += TPB){
        unsigned long long kj = ((unsigned long long)bin_u[jj] << 32)
                              | (unsigned long long)(unsigned)(~(unsigned)bin_i[jj]);
        int rank = 0;
        for (int k = 0; k < bn; ++k){
          unsigned long long kk2 = ((unsigned long long)bin_u[k] << 32)
                                 | (unsigned long long)(unsigned)(~(unsigned)bin_i[k]);
          rank += (kk2 > kj) ? 1 : 0;
        }
        if (rank < R){
          int sl = atomicAdd(&vcnt, 1);
          if (sl < KTOP) vidx[sl] = bin_i[jj];
        }
      }
      int na = min(cnt_ab, KTOP);
      for (int jj = tid; jj < na; jj += TPB){
        int sl = atomicAdd(&vcnt, 1);
        if (sl < KTOP) vidx[sl] = ab_i[jj];
      }
    } else {
      // T <= 32: every candidate is valid
      scan_sc([&](float sc, int idx){
        (void)sc;
        if (is_cand(idx)){
          int sl = atomicAdd(&vcnt, 1);
          if (sl < KTOP) vidx[sl] = idx;
        }
      });
    }
  }
  __syncthreads();

  // ---- LSE over the <=32 valid logits (wave 0, shuffle-parallel) ----
  int c = min(vcnt, KTOP);
  if (tid < c) vlog[tid] = logits[vidx[tid]];
  __syncthreads();
  if (tid < 64){
    float v = (tid < c) ? vlog[tid] : -FLT_MAX;
    float m = v;
    #pragma unroll
    for (int d = 32; d; d >>= 1) m = fmaxf(m, __shfl_xor(m, d));
    float ex = (tid < c) ? expf(v - m) : 0.f;
    #pragma unroll
    for (int d = 32; d; d >>= 1) ex += __shfl_xor(ex, d);
    if (tid == 0){
      float stop = stop_logits[g];              // TEMP == 1.0
      float logden;
      if (c == 0){
        logden = stop;                          // logaddexp(~-inf, stop) = stop
      } else {
        float lse = logf(fmaxf(ex, FLT_EPSILON)) + m;   // eps clamp per reference
        float mx = fmaxf(lse, stop);
        float dd = fabsf(lse - stop);
        logden = mx + log1pf(expf(-dd));        // logaddexp(lse, stop)
      }
      sh_logden = logden;
    }
  }
  __syncthreads();

  // ---- scatter the <=32 valid log-probs over the sentinel fill ----
  if (tid < c){
    float val = vlog[tid] - sh_logden;
    if (!(val >= -VCLAMP)) val = -VCLAMP;       // flushes NaN too
    if (val > VCLAMP)      val =  VCLAMP;
    out[vidx[tid]] = val;
  }
}

extern "C" void kernel_launch(void* const* d_in, const int* in_sizes, int n_in,
                              void* d_out, int out_size, void* d_ws, size_t ws_size,
                              hipStream_t stream){
  const float* edge_logits = (const float*)d_in[0];
  const float* edge_scores = (const float*)d_in[1];
  const float* stop_logits = (const float*)d_in[2];
  const int*   edge_batch  = (const int*)d_in[3];
  const int*   cmask       = (const int*)d_in[4];
  int E  = in_sizes[0];
  int NG = in_sizes[2];
  float* out = (float*)d_out;
  (void)d_ws; (void)ws_size;

  hipLaunchKernelGGL(fused_kernel, dim3(NG), dim3(TPB), 0, stream,
                     edge_logits, edge_scores, stop_logits, edge_batch, cmask,
                     out, E, NG);
}